// Round 15
// baseline (142.244 us; speedup 1.0000x reference)
//
#include <hip/hip_runtime.h>
#include <hip/hip_fp16.h>
#include <math.h>

// Net_Without_GINEgPool: GATConv(32,128,h=4) + TopKPooling(0.8) + max/mean pool + MLP head.
// R15: R12 structure (best: 117.5us). mlp fused into pool_partial via last-block-done
//      (512 blocks unchanged; 16th block per graph runs the MLP inline) -> one fewer
//      launch boundary. stage1 back to NPB=32 (R14's NPB=16 cost ~5us in W-prologue).

#define N_NODES 32000
#define B_GRAPHS 32
#define NPG 1000
#define DEGC 10
#define E_EDGES (N_NODES*DEGC)
#define HD 512
#define F_IN 32
#define KKEEP 800
#define SLOPE 0.2f
#define CAP 32

// ---------------- prep (block 0) + zero counts (blocks 1..32) ----------------
__global__ void prep_kernel(const float* __restrict__ W, const float* __restrict__ att_src,
                            const float* __restrict__ att_dst, const float* __restrict__ topk_w,
                            float* __restrict__ Ws, float* __restrict__ Wd, float* __restrict__ misc,
                            int* __restrict__ counts, int* __restrict__ done)
{
    int tid = threadIdx.x; // 256
    if (blockIdx.x > 0) {
        int i = (blockIdx.x - 1)*256 + tid;
        if (i < N_NODES/4) ((int4*)counts)[i] = make_int4(0,0,0,0);
        return;
    }
    if (tid < B_GRAPHS) done[tid] = 0;
    if (tid < 128) {
        int f = tid >> 2, hh = tid & 3;
        float s1 = 0.f, s2 = 0.f;
        for (int d = 0; d < 128; ++d) {
            float w = W[f*HD + hh*128 + d];
            s1 = fmaf(w, att_src[hh*128 + d], s1);
            s2 = fmaf(w, att_dst[hh*128 + d], s2);
        }
        Ws[f*4+hh] = s1;
        Wd[f*4+hh] = s2;
    }
    __shared__ float red[256];
    float tw0 = topk_w[tid], tw1 = topk_w[tid+256];
    red[tid] = tw0*tw0 + tw1*tw1;
    __syncthreads();
    for (int s = 128; s > 0; s >>= 1) { if (tid < s) red[tid] += red[tid+s]; __syncthreads(); }
    if (tid == 0) misc[0] = 1.0f / sqrtf(red[0]);
}

// ---------------- stage1: compute_h (XCD-aligned, NPB=32) | build_slots ----------------
#define NPB 32
#define CH_BLOCKS 1000
#define BS_BLOCKS 128
__global__ __launch_bounds__(256) void stage1_kernel(
    const float* __restrict__ x, const float* __restrict__ W,
    const float* __restrict__ Ws, const float* __restrict__ Wd,
    const int* __restrict__ dst,
    __half* __restrict__ h, float* __restrict__ a_s, float* __restrict__ a_d,
    int* __restrict__ counts, int* __restrict__ slots)
{
    int b = blockIdx.x;
    int tid = threadIdx.x;            // 256
    if (b < CH_BLOCKS) {
        __shared__ float s_x[NPB*F_IN];   // 4 KB
        int n0 = (b & 7)*4000 + (b >> 3)*NPB;
        float wc0[F_IN], wc1[F_IN];
        #pragma unroll
        for (int f = 0; f < F_IN; ++f) {
            float2 wp = *(const float2*)(W + f*HD + 2*tid);
            wc0[f] = wp.x;
            wc1[f] = wp.y;
        }
        const float4* xg = (const float4*)(x + (size_t)n0*F_IN);
        float4* sx4 = (float4*)s_x;
        if (tid < NPB*F_IN/4) sx4[tid] = xg[tid];
        __syncthreads();
        for (int n = 0; n < NPB; ++n) {
            const float4* xr = (const float4*)(s_x + n*F_IN);
            float acc0 = 0.f, acc1 = 0.f;
            #pragma unroll
            for (int f4 = 0; f4 < F_IN/4; ++f4) {
                float4 xv = xr[f4];
                acc0 = fmaf(xv.x, wc0[f4*4+0], acc0); acc1 = fmaf(xv.x, wc1[f4*4+0], acc1);
                acc0 = fmaf(xv.y, wc0[f4*4+1], acc0); acc1 = fmaf(xv.y, wc1[f4*4+1], acc1);
                acc0 = fmaf(xv.z, wc0[f4*4+2], acc0); acc1 = fmaf(xv.z, wc1[f4*4+2], acc1);
                acc0 = fmaf(xv.w, wc0[f4*4+3], acc0); acc1 = fmaf(xv.w, wc1[f4*4+3], acc1);
            }
            *(__half2*)(h + (size_t)(n0+n)*HD + 2*tid) = __floats2half2_rn(acc0, acc1);
        }
        {
            int n = tid >> 3, hh = (tid >> 1) & 3, which = tid & 1;
            const float* Wx = which ? Wd : Ws;
            const float* xr = s_x + n*F_IN;
            float s = 0.f;
            #pragma unroll
            for (int f = 0; f < F_IN; ++f) s = fmaf(xr[f], Wx[f*4+hh], s);
            float* dp = which ? a_d : a_s;
            dp[(size_t)(n0+n)*4 + hh] = s;
        }
    } else {
        int i = (b - CH_BLOCKS)*256 + tid;
        int stride = BS_BLOCKS*256;
        for (; i < E_EDGES; i += stride) {
            int d = dst[i];
            int p = atomicAdd(&counts[d], 1);
            if (p < CAP) slots[d*CAP + p] = i;
        }
    }
}

// ---------------- wave-per-node GAT: 8 cols/lane, 4-edge batched gathers ----------------
__global__ __launch_bounds__(256) void gat_agg_kernel(
    const __half* __restrict__ h, const float* __restrict__ a_s, const float* __restrict__ a_d,
    const int* __restrict__ counts, const int* __restrict__ slots, const int* __restrict__ esrc,
    const float* __restrict__ bias, const float* __restrict__ topk_w, const float* __restrict__ misc,
    __half* __restrict__ x1, float* __restrict__ scores)
{
    __shared__ int    s_src[4][CAP];
    __shared__ float4 s_al4[4][CAP];
    int tid = threadIdx.x;
    int wid = tid >> 6, lane = tid & 63;
    int grp  = (blockIdx.x & 7) * 1000 + (blockIdx.x >> 3);
    int node = grp*4 + wid;
    int deg  = min(counts[node], CAP);

    int src = node;
    if (lane < deg) src = esrc[slots[node*CAP + lane]];

    float4 ad    = *(const float4*)(a_d + (size_t)node*4);
    float4 aself = *(const float4*)(a_s + (size_t)node*4);
    float4 asrc  = make_float4(0.f,0.f,0.f,0.f);
    if (lane < deg) asrc = *(const float4*)(a_s + (size_t)src*4);

    float ex[4], exs[4];
    {
        float u;
        u = asrc.x + ad.x;  ex[0]  = u > 0.f ? u : SLOPE*u;
        u = asrc.y + ad.y;  ex[1]  = u > 0.f ? u : SLOPE*u;
        u = asrc.z + ad.z;  ex[2]  = u > 0.f ? u : SLOPE*u;
        u = asrc.w + ad.w;  ex[3]  = u > 0.f ? u : SLOPE*u;
        u = aself.x + ad.x; exs[0] = __expf(u > 0.f ? u : SLOPE*u);
        u = aself.y + ad.y; exs[1] = __expf(u > 0.f ? u : SLOPE*u);
        u = aself.z + ad.z; exs[2] = __expf(u > 0.f ? u : SLOPE*u);
        u = aself.w + ad.w; exs[3] = __expf(u > 0.f ? u : SLOPE*u);
    }
    float al[4], alself[4];
    #pragma unroll
    for (int hh = 0; hh < 4; ++hh) {
        float e = (lane < deg) ? __expf(ex[hh]) : 0.f;
        float den = e;
        #pragma unroll
        for (int msk = 1; msk < 64; msk <<= 1) den += __shfl_xor(den, msk, 64);
        den += exs[hh];
        float inv = __builtin_amdgcn_rcpf(den);
        al[hh]     = e * inv;
        alself[hh] = exs[hh] * inv;
    }
    if (lane < deg) {
        s_src[wid][lane] = src;
        s_al4[wid][lane] = make_float4(al[0], al[1], al[2], al[3]);
    }
    __syncthreads();

    int head = lane >> 4;
    const __half* hb = h + lane*8;
    const float* alw = (const float*)&s_al4[wid][0];
    float f0=0.f,f1=0.f,f2=0.f,f3=0.f,f4=0.f,f5=0.f,f6=0.f,f7=0.f;
    #define MIX_LO(ACC,A,Q) asm("v_fma_mix_f32 %0, %1, %2, %0 op_sel_hi:[0,1,0]" : "+v"(ACC) : "v"(A), "v"(Q))
    #define MIX_HI(ACC,A,Q) asm("v_fma_mix_f32 %0, %1, %2, %0 op_sel:[0,1,0] op_sel_hi:[0,1,0]" : "+v"(ACC) : "v"(A), "v"(Q))
    #define MIX8(AV,Q) { \
        MIX_LO(f0, AV, Q.x); MIX_HI(f1, AV, Q.x); \
        MIX_LO(f2, AV, Q.y); MIX_HI(f3, AV, Q.y); \
        MIX_LO(f4, AV, Q.z); MIX_HI(f5, AV, Q.z); \
        MIX_LO(f6, AV, Q.w); MIX_HI(f7, AV, Q.w); }
    int e = 0;
    for (; e + 4 <= deg; e += 4) {
        int se0 = s_src[wid][e],   se1 = s_src[wid][e+1];
        int se2 = s_src[wid][e+2], se3 = s_src[wid][e+3];
        float av0 = alw[(e+0)*4 + head], av1 = alw[(e+1)*4 + head];
        float av2 = alw[(e+2)*4 + head], av3 = alw[(e+3)*4 + head];
        uint4 q0 = *(const uint4*)(hb + (size_t)se0*HD);
        uint4 q1 = *(const uint4*)(hb + (size_t)se1*HD);
        uint4 q2 = *(const uint4*)(hb + (size_t)se2*HD);
        uint4 q3 = *(const uint4*)(hb + (size_t)se3*HD);
        MIX8(av0, q0) MIX8(av1, q1) MIX8(av2, q2) MIX8(av3, q3)
    }
    for (; e < deg; ++e) {
        int se = s_src[wid][e];
        float av = alw[e*4 + head];
        uint4 q = *(const uint4*)(hb + (size_t)se*HD);
        MIX8(av, q)
    }
    {
        float a01 = (head & 1) ? alself[1] : alself[0];
        float a23 = (head & 1) ? alself[3] : alself[2];
        float av  = (head & 2) ? a23 : a01;
        uint4 q = *(const uint4*)(hb + (size_t)node*HD);
        MIX8(av, q)
    }
    #undef MIX8
    #undef MIX_LO
    #undef MIX_HI

    int c0 = lane*8;
    float4 b0 = *(const float4*)(bias + c0);
    float4 b1 = *(const float4*)(bias + c0 + 4);
    float v0 = fmaxf(f0 + b0.x, 0.f), v1 = fmaxf(f1 + b0.y, 0.f);
    float v2 = fmaxf(f2 + b0.z, 0.f), v3 = fmaxf(f3 + b0.w, 0.f);
    float v4 = fmaxf(f4 + b1.x, 0.f), v5 = fmaxf(f5 + b1.y, 0.f);
    float v6 = fmaxf(f6 + b1.z, 0.f), v7 = fmaxf(f7 + b1.w, 0.f);
    {
        __half2 p0 = __floats2half2_rn(v0, v1);
        __half2 p1 = __floats2half2_rn(v2, v3);
        __half2 p2 = __floats2half2_rn(v4, v5);
        __half2 p3 = __floats2half2_rn(v6, v7);
        uint4 pk;
        pk.x = *(unsigned*)&p0; pk.y = *(unsigned*)&p1;
        pk.z = *(unsigned*)&p2; pk.w = *(unsigned*)&p3;
        *(uint4*)(x1 + (size_t)node*HD + c0) = pk;
    }

    float4 tw0 = *(const float4*)(topk_w + c0);
    float4 tw1 = *(const float4*)(topk_w + c0 + 4);
    float p = v0*tw0.x + v1*tw0.y + v2*tw0.z + v3*tw0.w
            + v4*tw1.x + v5*tw1.y + v6*tw1.z + v7*tw1.w;
    #pragma unroll
    for (int msk = 1; msk < 64; msk <<= 1) p += __shfl_xor(p, msk, 64);
    if (lane == 0) {
        float dotv = p * misc[0];
        float eu   = __expf(2.f * fabsf(dotv));
        float th   = 1.f - 2.f/(eu + 1.f);
        scores[node] = copysignf(th, dotv);
    }
}

// ---------------- TopK per graph via exact rank; 4 blocks/graph ----------------
__global__ __launch_bounds__(256) void topk_kernel(const float* __restrict__ scores,
                                                   int* __restrict__ kept_ids,
                                                   float* __restrict__ kept_vals)
{
    int g = blockIdx.x, part = blockIdx.y;
    __shared__ float s[NPG];
    int tid = threadIdx.x;
    for (int i = tid; i < NPG; i += 256) s[i] = scores[g*NPG + i];
    __syncthreads();
    int i = part*250 + tid;
    if (tid < 250) {
        float si = s[i];
        int rank = 0;
        for (int j = 0; j < NPG; ++j) {
            float sj = s[j];
            rank += (sj > si) || (sj == si && j < i);
        }
        if (rank < KKEEP) {
            kept_ids[g*KKEEP + rank]  = g*NPG + i;
            kept_vals[g*KKEEP + rank] = si;
        }
    }
}

// ---------------- pool partials + last-block MLP (fused, 512 blocks x 128 thr) ----------------
#define RCHUNK 50
#define NCHUNK 16
__global__ __launch_bounds__(128) void pool_mlp_kernel(
    const __half* __restrict__ x1, const int* __restrict__ kept_ids,
    const float* __restrict__ kept_vals, float* __restrict__ pmax, float* __restrict__ psum,
    int* __restrict__ done,
    const float* __restrict__ w1, const float* __restrict__ b1,
    const float* __restrict__ w2, const float* __restrict__ b2,
    const float* __restrict__ w3, const float* __restrict__ b3,
    float* __restrict__ out)
{
    int bid = blockIdx.x;                 // 512
    int k = bid & 7, q = bid >> 3;        // XCD k serves graphs 4k..4k+3
    int g = k*4 + (q & 3), c = q >> 2;    // c in [0,16)
    int tid = threadIdx.x;                // 128, 4-col group = tid*4
    __shared__ int   ids[RCHUNK];
    __shared__ float vals[RCHUNK];
    if (tid < RCHUNK) {
        ids[tid]  = kept_ids[g*KKEEP + c*RCHUNK + tid];
        vals[tid] = kept_vals[g*KKEEP + c*RCHUNK + tid];
    }
    __syncthreads();
    float4 mxA = make_float4(-INFINITY,-INFINITY,-INFINITY,-INFINITY), mxB = mxA;
    float4 smA = make_float4(0.f,0.f,0.f,0.f), smB = smA;
    for (int r = 0; r < RCHUNK; r += 2) {
        const __half2* pA = (const __half2*)(x1 + (size_t)ids[r]*HD + tid*4);
        const __half2* pB = (const __half2*)(x1 + (size_t)ids[r+1]*HD + tid*4);
        __half2 qA0 = pA[0], qA1 = pA[1], qB0 = pB[0], qB1 = pB[1];
        float2 a0 = __half22float2(qA0), a1 = __half22float2(qA1);
        float2 b0 = __half22float2(qB0), b1 = __half22float2(qB1);
        float lA = vals[r], lB = vals[r+1];
        float4 vA = make_float4(a0.x*lA, a0.y*lA, a1.x*lA, a1.y*lA);
        float4 vB = make_float4(b0.x*lB, b0.y*lB, b1.x*lB, b1.y*lB);
        mxA.x = fmaxf(mxA.x, vA.x); mxA.y = fmaxf(mxA.y, vA.y);
        mxA.z = fmaxf(mxA.z, vA.z); mxA.w = fmaxf(mxA.w, vA.w);
        mxB.x = fmaxf(mxB.x, vB.x); mxB.y = fmaxf(mxB.y, vB.y);
        mxB.z = fmaxf(mxB.z, vB.z); mxB.w = fmaxf(mxB.w, vB.w);
        smA.x += vA.x; smA.y += vA.y; smA.z += vA.z; smA.w += vA.w;
        smB.x += vB.x; smB.y += vB.y; smB.z += vB.z; smB.w += vB.w;
    }
    float4 mx, sm;
    mx.x = fmaxf(mxA.x, mxB.x); mx.y = fmaxf(mxA.y, mxB.y);
    mx.z = fmaxf(mxA.z, mxB.z); mx.w = fmaxf(mxA.w, mxB.w);
    sm.x = smA.x + smB.x; sm.y = smA.y + smB.y;
    sm.z = smA.z + smB.z; sm.w = smA.w + smB.w;
    *(float4*)(pmax + (size_t)(g*NCHUNK + c)*HD + tid*4) = mx;
    *(float4*)(psum + (size_t)(g*NCHUNK + c)*HD + tid*4) = sm;

    // ---- last-block-done: 16th block of graph g runs the MLP inline ----
    __threadfence();                         // make partials visible device-wide
    __shared__ int amlast;
    if (tid == 0) amlast = (atomicAdd(&done[g], 1) == NCHUNK - 1);
    __syncthreads();
    if (!amlast) return;
    __threadfence();                         // acquire: see all 16 partials

    __shared__ float sx[1024];
    __shared__ float part1[4][128];
    __shared__ float sh1[128];
    __shared__ float part2[2][64];
    __shared__ float sh2[64];
    __shared__ float part3[8][8];
    __shared__ float slog[8];

    {   // pool finalize over 16 partials; thread owns float4 col tid (max) then (mean)
        float4 rm = *(const float4*)(pmax + (size_t)(g*NCHUNK)*HD + tid*4);
        float4 rs = *(const float4*)(psum + (size_t)(g*NCHUNK)*HD + tid*4);
        #pragma unroll
        for (int cc = 1; cc < NCHUNK; ++cc) {
            float4 vm = *(const float4*)(pmax + (size_t)(g*NCHUNK + cc)*HD + tid*4);
            float4 vs = *(const float4*)(psum + (size_t)(g*NCHUNK + cc)*HD + tid*4);
            rm.x = fmaxf(rm.x, vm.x); rm.y = fmaxf(rm.y, vm.y);
            rm.z = fmaxf(rm.z, vm.z); rm.w = fmaxf(rm.w, vm.w);
            rs.x += vs.x; rs.y += vs.y; rs.z += vs.z; rs.w += vs.w;
        }
        const float inv = 1.0f/KKEEP;
        rs.x *= inv; rs.y *= inv; rs.z *= inv; rs.w *= inv;
        *(float4*)(sx + tid*4)       = rm;
        *(float4*)(sx + 512 + tid*4) = rs;
    }
    __syncthreads();

    {   // layer 1: 1024 -> 128, 4 k-slices of 256
        int ks = tid >> 5, tc = tid & 31;
        const float* w1p = w1 + (size_t)(ks*256)*128 + tc*4;
        const float* sxp = sx + ks*256;
        float4 acc = make_float4(0.f,0.f,0.f,0.f);
        #pragma unroll 8
        for (int kk = 0; kk < 256; ++kk) {
            float xk = sxp[kk];
            float4 w = *(const float4*)(w1p + (size_t)kk*128);
            acc.x = fmaf(xk, w.x, acc.x); acc.y = fmaf(xk, w.y, acc.y);
            acc.z = fmaf(xk, w.z, acc.z); acc.w = fmaf(xk, w.w, acc.w);
        }
        *(float4*)(&part1[ks][tc*4]) = acc;
    }
    __syncthreads();
    {
        float s = b1[tid];
        #pragma unroll
        for (int p = 0; p < 4; ++p) s += part1[p][tid];
        sh1[tid] = fmaxf(s, 0.0f);
    }
    __syncthreads();

    {   // layer 2: 128 -> 64, 2 k-slices of 64
        int ks2 = tid >> 6, to = tid & 63;
        float a = 0.f;
        #pragma unroll 8
        for (int kk = 0; kk < 64; ++kk) {
            int kx = ks2*64 + kk;
            a = fmaf(sh1[kx], w2[kx*64 + to], a);
        }
        part2[ks2][to] = a;
    }
    __syncthreads();
    if (tid < 64) {
        float s = b2[tid];
        s += part2[0][tid] + part2[1][tid];
        sh2[tid] = fmaxf(s, 0.0f);
    }
    __syncthreads();

    if (tid < 64) {   // layer 3: 64 -> 8, 8 k-slices of 8
        int ks3 = tid >> 3, o = tid & 7;
        float a = 0.f;
        #pragma unroll
        for (int kk = 0; kk < 8; ++kk) {
            int kx = ks3*8 + kk;
            a = fmaf(sh2[kx], w3[kx*8 + o], a);
        }
        part3[ks3][o] = a;
    }
    __syncthreads();
    if (tid < 8) {
        float s = b3[tid];
        #pragma unroll
        for (int p = 0; p < 8; ++p) s += part3[p][tid];
        slog[tid] = s;
    }
    __syncthreads();
    if (tid == 0) {
        float m = slog[0];
        for (int i = 1; i < 8; ++i) m = fmaxf(m, slog[i]);
        float ssum = 0.0f;
        for (int i = 0; i < 8; ++i) ssum += expf(slog[i] - m);
        float lse = m + logf(ssum);
        for (int i = 0; i < 8; ++i) out[g*8 + i] = slog[i] - lse;
    }
}

extern "C" void kernel_launch(void* const* d_in, const int* in_sizes, int n_in,
                              void* d_out, int out_size, void* d_ws, size_t ws_size,
                              hipStream_t stream) {
    const float* x        = (const float*)d_in[0];
    const int*   ei       = (const int*)d_in[1];
    const float* W        = (const float*)d_in[4];
    const float* att_src  = (const float*)d_in[5];
    const float* att_dst  = (const float*)d_in[6];
    const float* bias     = (const float*)d_in[7];
    const float* topk_w   = (const float*)d_in[8];
    const float* w1       = (const float*)d_in[9];
    const float* b1       = (const float*)d_in[10];
    const float* w2       = (const float*)d_in[11];
    const float* b2       = (const float*)d_in[12];
    const float* w3       = (const float*)d_in[13];
    const float* b3       = (const float*)d_in[14];
    float* out = (float*)d_out;

    const int* src = ei;
    const int* dst = ei + E_EDGES;

    char* wsb = (char*)d_ws;
    size_t off = 0;
    auto alloc = [&](size_t bytes) -> void* {
        void* p = (void*)(wsb + off);
        off += (bytes + 255) & ~(size_t)255;
        return p;
    };
    __half* h       = (__half*)alloc((size_t)N_NODES*HD*2);
    __half* x1      = (__half*)alloc((size_t)N_NODES*HD*2);
    float* a_s      = (float*)alloc((size_t)N_NODES*4*4);
    float* a_d      = (float*)alloc((size_t)N_NODES*4*4);
    float* Ws       = (float*)alloc(F_IN*4*4);
    float* Wd       = (float*)alloc(F_IN*4*4);
    float* misc     = (float*)alloc(256);
    int*   counts   = (int*)alloc((size_t)N_NODES*4);
    int*   slots    = (int*)alloc((size_t)N_NODES*CAP*4);
    float* scores   = (float*)alloc((size_t)N_NODES*4);
    int*   kept_ids = (int*)alloc((size_t)B_GRAPHS*KKEEP*4);
    float* kept_vals= (float*)alloc((size_t)B_GRAPHS*KKEEP*4);
    float* pmax     = (float*)alloc((size_t)B_GRAPHS*NCHUNK*HD*4);
    float* psum     = (float*)alloc((size_t)B_GRAPHS*NCHUNK*HD*4);
    int*   done     = (int*)alloc((size_t)B_GRAPHS*4);

    prep_kernel<<<33, 256, 0, stream>>>(W, att_src, att_dst, topk_w, Ws, Wd, misc, counts, done);
    stage1_kernel<<<CH_BLOCKS + BS_BLOCKS, 256, 0, stream>>>(
        x, W, Ws, Wd, dst, h, a_s, a_d, counts, slots);
    gat_agg_kernel<<<N_NODES/4, 256, 0, stream>>>(h, a_s, a_d, counts, slots, src,
                                                  bias, topk_w, misc, x1, scores);
    topk_kernel<<<dim3(B_GRAPHS, 4), 256, 0, stream>>>(scores, kept_ids, kept_vals);
    pool_mlp_kernel<<<B_GRAPHS*NCHUNK, 128, 0, stream>>>(x1, kept_ids, kept_vals, pmax, psum,
                                                         done, w1, b1, w2, b2, w3, b3, out);
}

// Round 17
// 117.377 us; speedup vs baseline: 1.2119x; 1.2119x over previous
//
#include <hip/hip_runtime.h>
#include <hip/hip_fp16.h>
#include <math.h>

// Net_Without_GINEgPool: GATConv(32,128,h=4) + TopKPooling(0.8) + max/mean pool + MLP head.
// R17 = R12 verbatim (proven best: 117.5us, absmax 0.0156).
//   prep(33 blk: fold att + zero counts) -> stage1(compute_h XCD-aligned NPB=32 +
//   build_slots) -> gat_agg(wave/node, 8col/lane uint4 gathers, fma_mix, no-max softmax,
//   fp16 h/x1) -> topk(128 blk exact-rank) -> pool_partial(512 blk) -> mlp(k-split).
// R13-R16 experiments (tail vectorization, NPB=16, fence-fusion, rank-in-pool) all
// regressed or broke numerics; launch-boundary overhead (~40us) resists fusion on
// this runtime without width collapse / fences / reduction-order changes.

#define N_NODES 32000
#define B_GRAPHS 32
#define NPG 1000
#define DEGC 10
#define E_EDGES (N_NODES*DEGC)
#define HD 512
#define F_IN 32
#define KKEEP 800
#define SLOPE 0.2f
#define CAP 32

// ---------------- prep (block 0) + zero counts (blocks 1..32) ----------------
__global__ void prep_kernel(const float* __restrict__ W, const float* __restrict__ att_src,
                            const float* __restrict__ att_dst, const float* __restrict__ topk_w,
                            float* __restrict__ Ws, float* __restrict__ Wd, float* __restrict__ misc,
                            int* __restrict__ counts)
{
    int tid = threadIdx.x; // 256
    if (blockIdx.x > 0) {
        int i = (blockIdx.x - 1)*256 + tid;
        if (i < N_NODES/4) ((int4*)counts)[i] = make_int4(0,0,0,0);
        return;
    }
    if (tid < 128) {
        int f = tid >> 2, hh = tid & 3;
        float s1 = 0.f, s2 = 0.f;
        for (int d = 0; d < 128; ++d) {
            float w = W[f*HD + hh*128 + d];
            s1 = fmaf(w, att_src[hh*128 + d], s1);
            s2 = fmaf(w, att_dst[hh*128 + d], s2);
        }
        Ws[f*4+hh] = s1;
        Wd[f*4+hh] = s2;
    }
    __shared__ float red[256];
    float tw0 = topk_w[tid], tw1 = topk_w[tid+256];
    red[tid] = tw0*tw0 + tw1*tw1;
    __syncthreads();
    for (int s = 128; s > 0; s >>= 1) { if (tid < s) red[tid] += red[tid+s]; __syncthreads(); }
    if (tid == 0) misc[0] = 1.0f / sqrtf(red[0]);
}

// ---------------- stage1: compute_h (XCD-aligned, NPB=32) | build_slots ----------------
#define NPB 32
#define CH_BLOCKS 1000
#define BS_BLOCKS 128
__global__ __launch_bounds__(256) void stage1_kernel(
    const float* __restrict__ x, const float* __restrict__ W,
    const float* __restrict__ Ws, const float* __restrict__ Wd,
    const int* __restrict__ dst,
    __half* __restrict__ h, float* __restrict__ a_s, float* __restrict__ a_d,
    int* __restrict__ counts, int* __restrict__ slots)
{
    int b = blockIdx.x;
    int tid = threadIdx.x;            // 256
    if (b < CH_BLOCKS) {
        __shared__ float s_x[NPB*F_IN];   // 4 KB
        int n0 = (b & 7)*4000 + (b >> 3)*NPB;
        float wc0[F_IN], wc1[F_IN];
        #pragma unroll
        for (int f = 0; f < F_IN; ++f) {
            float2 wp = *(const float2*)(W + f*HD + 2*tid);
            wc0[f] = wp.x;
            wc1[f] = wp.y;
        }
        const float4* xg = (const float4*)(x + (size_t)n0*F_IN);
        float4* sx4 = (float4*)s_x;
        if (tid < NPB*F_IN/4) sx4[tid] = xg[tid];
        __syncthreads();
        for (int n = 0; n < NPB; ++n) {
            const float4* xr = (const float4*)(s_x + n*F_IN);
            float acc0 = 0.f, acc1 = 0.f;
            #pragma unroll
            for (int f4 = 0; f4 < F_IN/4; ++f4) {
                float4 xv = xr[f4];
                acc0 = fmaf(xv.x, wc0[f4*4+0], acc0); acc1 = fmaf(xv.x, wc1[f4*4+0], acc1);
                acc0 = fmaf(xv.y, wc0[f4*4+1], acc0); acc1 = fmaf(xv.y, wc1[f4*4+1], acc1);
                acc0 = fmaf(xv.z, wc0[f4*4+2], acc0); acc1 = fmaf(xv.z, wc1[f4*4+2], acc1);
                acc0 = fmaf(xv.w, wc0[f4*4+3], acc0); acc1 = fmaf(xv.w, wc1[f4*4+3], acc1);
            }
            *(__half2*)(h + (size_t)(n0+n)*HD + 2*tid) = __floats2half2_rn(acc0, acc1);
        }
        {
            int n = tid >> 3, hh = (tid >> 1) & 3, which = tid & 1;
            const float* Wx = which ? Wd : Ws;
            const float* xr = s_x + n*F_IN;
            float s = 0.f;
            #pragma unroll
            for (int f = 0; f < F_IN; ++f) s = fmaf(xr[f], Wx[f*4+hh], s);
            float* dp = which ? a_d : a_s;
            dp[(size_t)(n0+n)*4 + hh] = s;
        }
    } else {
        int i = (b - CH_BLOCKS)*256 + tid;
        int stride = BS_BLOCKS*256;
        for (; i < E_EDGES; i += stride) {
            int d = dst[i];
            int p = atomicAdd(&counts[d], 1);
            if (p < CAP) slots[d*CAP + p] = i;
        }
    }
}

// ---------------- wave-per-node GAT: 8 cols/lane, 4-edge batched gathers ----------------
__global__ __launch_bounds__(256) void gat_agg_kernel(
    const __half* __restrict__ h, const float* __restrict__ a_s, const float* __restrict__ a_d,
    const int* __restrict__ counts, const int* __restrict__ slots, const int* __restrict__ esrc,
    const float* __restrict__ bias, const float* __restrict__ topk_w, const float* __restrict__ misc,
    __half* __restrict__ x1, float* __restrict__ scores)
{
    __shared__ int    s_src[4][CAP];
    __shared__ float4 s_al4[4][CAP];
    int tid = threadIdx.x;
    int wid = tid >> 6, lane = tid & 63;
    // XCD swizzle: XCD k handles nodes [k*4000,(k+1)*4000)
    int grp  = (blockIdx.x & 7) * 1000 + (blockIdx.x >> 3);
    int node = grp*4 + wid;
    int deg  = min(counts[node], CAP);

    // edge order = slot order (atomic fill order); FP jitter ~1e-7 << threshold
    int src = node;
    if (lane < deg) src = esrc[slots[node*CAP + lane]];

    float4 ad    = *(const float4*)(a_d + (size_t)node*4);
    float4 aself = *(const float4*)(a_s + (size_t)node*4);
    float4 asrc  = make_float4(0.f,0.f,0.f,0.f);
    if (lane < deg) asrc = *(const float4*)(a_s + (size_t)src*4);

    float ex[4], exs[4];
    {
        float u;
        u = asrc.x + ad.x;  ex[0]  = u > 0.f ? u : SLOPE*u;
        u = asrc.y + ad.y;  ex[1]  = u > 0.f ? u : SLOPE*u;
        u = asrc.z + ad.z;  ex[2]  = u > 0.f ? u : SLOPE*u;
        u = asrc.w + ad.w;  ex[3]  = u > 0.f ? u : SLOPE*u;
        u = aself.x + ad.x; exs[0] = __expf(u > 0.f ? u : SLOPE*u);
        u = aself.y + ad.y; exs[1] = __expf(u > 0.f ? u : SLOPE*u);
        u = aself.z + ad.z; exs[2] = __expf(u > 0.f ? u : SLOPE*u);
        u = aself.w + ad.w; exs[3] = __expf(u > 0.f ? u : SLOPE*u);
    }
    float al[4], alself[4];
    #pragma unroll
    for (int hh = 0; hh < 4; ++hh) {
        float e = (lane < deg) ? __expf(ex[hh]) : 0.f;
        float den = e;
        #pragma unroll
        for (int msk = 1; msk < 64; msk <<= 1) den += __shfl_xor(den, msk, 64);
        den += exs[hh];
        float inv = __builtin_amdgcn_rcpf(den);
        al[hh]     = e * inv;
        alself[hh] = exs[hh] * inv;
    }
    if (lane < deg) {
        s_src[wid][lane] = src;
        s_al4[wid][lane] = make_float4(al[0], al[1], al[2], al[3]);
    }
    __syncthreads();

    // aggregation: lane owns 8 contiguous cols [lane*8,+8); head = lane>>4
    int head = lane >> 4;
    const __half* hb = h + lane*8;
    const float* alw = (const float*)&s_al4[wid][0];
    float f0=0.f,f1=0.f,f2=0.f,f3=0.f,f4=0.f,f5=0.f,f6=0.f,f7=0.f;
    #define MIX_LO(ACC,A,Q) asm("v_fma_mix_f32 %0, %1, %2, %0 op_sel_hi:[0,1,0]" : "+v"(ACC) : "v"(A), "v"(Q))
    #define MIX_HI(ACC,A,Q) asm("v_fma_mix_f32 %0, %1, %2, %0 op_sel:[0,1,0] op_sel_hi:[0,1,0]" : "+v"(ACC) : "v"(A), "v"(Q))
    #define MIX8(AV,Q) { \
        MIX_LO(f0, AV, Q.x); MIX_HI(f1, AV, Q.x); \
        MIX_LO(f2, AV, Q.y); MIX_HI(f3, AV, Q.y); \
        MIX_LO(f4, AV, Q.z); MIX_HI(f5, AV, Q.z); \
        MIX_LO(f6, AV, Q.w); MIX_HI(f7, AV, Q.w); }
    int e = 0;
    for (; e + 4 <= deg; e += 4) {       // 4 independent loads in flight, then 32 fma_mix
        int se0 = s_src[wid][e],   se1 = s_src[wid][e+1];
        int se2 = s_src[wid][e+2], se3 = s_src[wid][e+3];
        float av0 = alw[(e+0)*4 + head], av1 = alw[(e+1)*4 + head];
        float av2 = alw[(e+2)*4 + head], av3 = alw[(e+3)*4 + head];
        uint4 q0 = *(const uint4*)(hb + (size_t)se0*HD);
        uint4 q1 = *(const uint4*)(hb + (size_t)se1*HD);
        uint4 q2 = *(const uint4*)(hb + (size_t)se2*HD);
        uint4 q3 = *(const uint4*)(hb + (size_t)se3*HD);
        MIX8(av0, q0) MIX8(av1, q1) MIX8(av2, q2) MIX8(av3, q3)
    }
    for (; e < deg; ++e) {
        int se = s_src[wid][e];
        float av = alw[e*4 + head];
        uint4 q = *(const uint4*)(hb + (size_t)se*HD);
        MIX8(av, q)
    }
    {   // self-loop last (reference concat order); static-index alpha select
        float a01 = (head & 1) ? alself[1] : alself[0];
        float a23 = (head & 1) ? alself[3] : alself[2];
        float av  = (head & 2) ? a23 : a01;
        uint4 q = *(const uint4*)(hb + (size_t)node*HD);
        MIX8(av, q)
    }
    #undef MIX8
    #undef MIX_LO
    #undef MIX_HI

    int c0 = lane*8;
    float4 b0 = *(const float4*)(bias + c0);
    float4 b1 = *(const float4*)(bias + c0 + 4);
    float v0 = fmaxf(f0 + b0.x, 0.f), v1 = fmaxf(f1 + b0.y, 0.f);
    float v2 = fmaxf(f2 + b0.z, 0.f), v3 = fmaxf(f3 + b0.w, 0.f);
    float v4 = fmaxf(f4 + b1.x, 0.f), v5 = fmaxf(f5 + b1.y, 0.f);
    float v6 = fmaxf(f6 + b1.z, 0.f), v7 = fmaxf(f7 + b1.w, 0.f);
    {   // single 16B fp16 store
        __half2 p0 = __floats2half2_rn(v0, v1);
        __half2 p1 = __floats2half2_rn(v2, v3);
        __half2 p2 = __floats2half2_rn(v4, v5);
        __half2 p3 = __floats2half2_rn(v6, v7);
        uint4 pk;
        pk.x = *(unsigned*)&p0; pk.y = *(unsigned*)&p1;
        pk.z = *(unsigned*)&p2; pk.w = *(unsigned*)&p3;
        *(uint4*)(x1 + (size_t)node*HD + c0) = pk;
    }

    // topk score from fp32 accumulators
    float4 tw0 = *(const float4*)(topk_w + c0);
    float4 tw1 = *(const float4*)(topk_w + c0 + 4);
    float p = v0*tw0.x + v1*tw0.y + v2*tw0.z + v3*tw0.w
            + v4*tw1.x + v5*tw1.y + v6*tw1.z + v7*tw1.w;
    #pragma unroll
    for (int msk = 1; msk < 64; msk <<= 1) p += __shfl_xor(p, msk, 64);
    if (lane == 0) {
        float dotv = p * misc[0];
        float eu   = __expf(2.f * fabsf(dotv));
        float th   = 1.f - 2.f/(eu + 1.f);
        scores[node] = copysignf(th, dotv);
    }
}

// ---------------- TopK per graph via exact rank; 4 blocks/graph ----------------
__global__ __launch_bounds__(256) void topk_kernel(const float* __restrict__ scores,
                                                   int* __restrict__ kept_ids,
                                                   float* __restrict__ kept_vals)
{
    int g = blockIdx.x, part = blockIdx.y;
    __shared__ float s[NPG];
    int tid = threadIdx.x;
    for (int i = tid; i < NPG; i += 256) s[i] = scores[g*NPG + i];
    __syncthreads();
    int i = part*250 + tid;
    if (tid < 250) {
        float si = s[i];
        int rank = 0;
        for (int j = 0; j < NPG; ++j) {
            float sj = s[j];
            rank += (sj > si) || (sj == si && j < i);
        }
        if (rank < KKEEP) {
            kept_ids[g*KKEEP + rank]  = g*NPG + i;
            kept_vals[g*KKEEP + rank] = si;
        }
    }
}

// ---------------- pool partials: 16 chunks x 50 rows, XCD-aligned, fp16 reads ----------------
#define RCHUNK 50
#define NCHUNK 16
__global__ __launch_bounds__(128) void pool_partial_kernel(
    const __half* __restrict__ x1, const int* __restrict__ kept_ids,
    const float* __restrict__ kept_vals, float* __restrict__ pmax, float* __restrict__ psum)
{
    int bid = blockIdx.x;                 // 512
    int k = bid & 7, q = bid >> 3;        // XCD k serves graphs 4k..4k+3
    int g = k*4 + (q & 3), c = q >> 2;    // c in [0,16)
    int tid = threadIdx.x;                // 128, 4-col group = tid*4
    __shared__ int   ids[RCHUNK];
    __shared__ float vals[RCHUNK];
    if (tid < RCHUNK) {
        ids[tid]  = kept_ids[g*KKEEP + c*RCHUNK + tid];
        vals[tid] = kept_vals[g*KKEEP + c*RCHUNK + tid];
    }
    __syncthreads();
    float4 mxA = make_float4(-INFINITY,-INFINITY,-INFINITY,-INFINITY), mxB = mxA;
    float4 smA = make_float4(0.f,0.f,0.f,0.f), smB = smA;
    for (int r = 0; r < RCHUNK; r += 2) {
        const __half2* pA = (const __half2*)(x1 + (size_t)ids[r]*HD + tid*4);
        const __half2* pB = (const __half2*)(x1 + (size_t)ids[r+1]*HD + tid*4);
        __half2 qA0 = pA[0], qA1 = pA[1], qB0 = pB[0], qB1 = pB[1];
        float2 a0 = __half22float2(qA0), a1 = __half22float2(qA1);
        float2 b0 = __half22float2(qB0), b1 = __half22float2(qB1);
        float lA = vals[r], lB = vals[r+1];
        float4 vA = make_float4(a0.x*lA, a0.y*lA, a1.x*lA, a1.y*lA);
        float4 vB = make_float4(b0.x*lB, b0.y*lB, b1.x*lB, b1.y*lB);
        mxA.x = fmaxf(mxA.x, vA.x); mxA.y = fmaxf(mxA.y, vA.y);
        mxA.z = fmaxf(mxA.z, vA.z); mxA.w = fmaxf(mxA.w, vA.w);
        mxB.x = fmaxf(mxB.x, vB.x); mxB.y = fmaxf(mxB.y, vB.y);
        mxB.z = fmaxf(mxB.z, vB.z); mxB.w = fmaxf(mxB.w, vB.w);
        smA.x += vA.x; smA.y += vA.y; smA.z += vA.z; smA.w += vA.w;
        smB.x += vB.x; smB.y += vB.y; smB.z += vB.z; smB.w += vB.w;
    }
    float4 mx, sm;
    mx.x = fmaxf(mxA.x, mxB.x); mx.y = fmaxf(mxA.y, mxB.y);
    mx.z = fmaxf(mxA.z, mxB.z); mx.w = fmaxf(mxA.w, mxB.w);
    sm.x = smA.x + smB.x; sm.y = smA.y + smB.y;
    sm.z = smA.z + smB.z; sm.w = smA.w + smB.w;
    *(float4*)(pmax + (size_t)(g*NCHUNK + c)*HD + tid*4) = mx;
    *(float4*)(psum + (size_t)(g*NCHUNK + c)*HD + tid*4) = sm;
}

// ---------------- finalize pool + MLP head (k-split, 256 threads) ----------------
__global__ __launch_bounds__(256) void mlp_kernel(
    const float* __restrict__ pmax, const float* __restrict__ psum,
    const float* __restrict__ w1, const float* __restrict__ b1,
    const float* __restrict__ w2, const float* __restrict__ b2,
    const float* __restrict__ w3, const float* __restrict__ b3,
    float* __restrict__ out)
{
    int g = blockIdx.x;
    int tid = threadIdx.x; // 256
    __shared__ float sx[1024];
    __shared__ float part1[8][128];
    __shared__ float sh1[128];
    __shared__ float part2[4][64];
    __shared__ float sh2[64];
    __shared__ float part3[8][8];
    __shared__ float slog[8];

    {   // pool finalize over 16 partials
        int half = tid >> 7;           // 0 = max, 1 = mean
        int c4 = tid & 127;
        const float* basep = half ? psum : pmax;
        float4 r = *(const float4*)(basep + (size_t)(g*NCHUNK)*HD + c4*4);
        #pragma unroll
        for (int c = 1; c < NCHUNK; ++c) {
            float4 v = *(const float4*)(basep + (size_t)(g*NCHUNK + c)*HD + c4*4);
            if (half) { r.x += v.x; r.y += v.y; r.z += v.z; r.w += v.w; }
            else {
                r.x = fmaxf(r.x, v.x); r.y = fmaxf(r.y, v.y);
                r.z = fmaxf(r.z, v.z); r.w = fmaxf(r.w, v.w);
            }
        }
        if (half) { const float inv = 1.0f/KKEEP; r.x *= inv; r.y *= inv; r.z *= inv; r.w *= inv; }
        *(float4*)(sx + half*512 + c4*4) = r;
    }
    __syncthreads();

    {   // layer 1: 1024 -> 128, 8 k-slices of 128
        int ks = tid >> 5, tc = tid & 31;
        const float* w1p = w1 + (size_t)(ks*128)*128 + tc*4;
        const float* sxp = sx + ks*128;
        float4 acc = make_float4(0.f,0.f,0.f,0.f);
        #pragma unroll 8
        for (int k = 0; k < 128; ++k) {
            float xk = sxp[k];
            float4 w = *(const float4*)(w1p + (size_t)k*128);
            acc.x = fmaf(xk, w.x, acc.x); acc.y = fmaf(xk, w.y, acc.y);
            acc.z = fmaf(xk, w.z, acc.z); acc.w = fmaf(xk, w.w, acc.w);
        }
        *(float4*)(&part1[ks][tc*4]) = acc;
    }
    __syncthreads();
    if (tid < 128) {
        float s = b1[tid];
        #pragma unroll
        for (int p = 0; p < 8; ++p) s += part1[p][tid];
        sh1[tid] = fmaxf(s, 0.0f);
    }
    __syncthreads();

    {   // layer 2: 128 -> 64, 4 k-slices of 32
        int ks2 = tid >> 6, to = tid & 63;
        float a = 0.f;
        #pragma unroll 8
        for (int k = 0; k < 32; ++k) {
            int kk = ks2*32 + k;
            a = fmaf(sh1[kk], w2[kk*64 + to], a);
        }
        part2[ks2][to] = a;
    }
    __syncthreads();
    if (tid < 64) {
        float s = b2[tid];
        #pragma unroll
        for (int p = 0; p < 4; ++p) s += part2[p][tid];
        sh2[tid] = fmaxf(s, 0.0f);
    }
    __syncthreads();

    if (tid < 64) {   // layer 3: 64 -> 8, 8 k-slices of 8
        int ks3 = tid >> 3, o = tid & 7;
        float a = 0.f;
        #pragma unroll
        for (int k = 0; k < 8; ++k) {
            int kk = ks3*8 + k;
            a = fmaf(sh2[kk], w3[kk*8 + o], a);
        }
        part3[ks3][o] = a;
    }
    __syncthreads();
    if (tid < 8) {
        float s = b3[tid];
        #pragma unroll
        for (int p = 0; p < 8; ++p) s += part3[p][tid];
        slog[tid] = s;
    }
    __syncthreads();
    if (tid == 0) {
        float m = slog[0];
        for (int i = 1; i < 8; ++i) m = fmaxf(m, slog[i]);
        float ssum = 0.0f;
        for (int i = 0; i < 8; ++i) ssum += expf(slog[i] - m);
        float lse = m + logf(ssum);
        for (int i = 0; i < 8; ++i) out[g*8 + i] = slog[i] - lse;
    }
}

extern "C" void kernel_launch(void* const* d_in, const int* in_sizes, int n_in,
                              void* d_out, int out_size, void* d_ws, size_t ws_size,
                              hipStream_t stream) {
    const float* x        = (const float*)d_in[0];
    const int*   ei       = (const int*)d_in[1];
    const float* W        = (const float*)d_in[4];
    const float* att_src  = (const float*)d_in[5];
    const float* att_dst  = (const float*)d_in[6];
    const float* bias     = (const float*)d_in[7];
    const float* topk_w   = (const float*)d_in[8];
    const float* w1       = (const float*)d_in[9];
    const float* b1       = (const float*)d_in[10];
    const float* w2       = (const float*)d_in[11];
    const float* b2       = (const float*)d_in[12];
    const float* w3       = (const float*)d_in[13];
    const float* b3       = (const float*)d_in[14];
    float* out = (float*)d_out;

    const int* src = ei;
    const int* dst = ei + E_EDGES;

    char* wsb = (char*)d_ws;
    size_t off = 0;
    auto alloc = [&](size_t bytes) -> void* {
        void* p = (void*)(wsb + off);
        off += (bytes + 255) & ~(size_t)255;
        return p;
    };
    __half* h       = (__half*)alloc((size_t)N_NODES*HD*2);
    __half* x1      = (__half*)alloc((size_t)N_NODES*HD*2);
    float* a_s      = (float*)alloc((size_t)N_NODES*4*4);
    float* a_d      = (float*)alloc((size_t)N_NODES*4*4);
    float* Ws       = (float*)alloc(F_IN*4*4);
    float* Wd       = (float*)alloc(F_IN*4*4);
    float* misc     = (float*)alloc(256);
    int*   counts   = (int*)alloc((size_t)N_NODES*4);
    int*   slots    = (int*)alloc((size_t)N_NODES*CAP*4);
    float* scores   = (float*)alloc((size_t)N_NODES*4);
    int*   kept_ids = (int*)alloc((size_t)B_GRAPHS*KKEEP*4);
    float* kept_vals= (float*)alloc((size_t)B_GRAPHS*KKEEP*4);
    float* pmax     = (float*)alloc((size_t)B_GRAPHS*NCHUNK*HD*4);
    float* psum     = (float*)alloc((size_t)B_GRAPHS*NCHUNK*HD*4);

    prep_kernel<<<33, 256, 0, stream>>>(W, att_src, att_dst, topk_w, Ws, Wd, misc, counts);
    stage1_kernel<<<CH_BLOCKS + BS_BLOCKS, 256, 0, stream>>>(
        x, W, Ws, Wd, dst, h, a_s, a_d, counts, slots);
    gat_agg_kernel<<<N_NODES/4, 256, 0, stream>>>(h, a_s, a_d, counts, slots, src,
                                                  bias, topk_w, misc, x1, scores);
    topk_kernel<<<dim3(B_GRAPHS, 4), 256, 0, stream>>>(scores, kept_ids, kept_vals);
    pool_partial_kernel<<<B_GRAPHS*NCHUNK, 128, 0, stream>>>(x1, kept_ids, kept_vals, pmax, psum);
    mlp_kernel<<<B_GRAPHS, 256, 0, stream>>>(pmax, psum, w1, b1, w2, b2, w3, b3, out);
}